// Round 1
// baseline (1195.657 us; speedup 1.0000x reference)
//
#include <hip/hip_runtime.h>
#include <math.h>

#define Hh 160
#define Ww 160
#define Cc 128
#define HW 25600
#define NPIX 102400   // N*H*W, N=4
#define NB 4

// ws layout (float offsets)
#define OFF_OFFS 0u
#define OFF_WT   1843200u      // 9*128*128 floats
#define OFF_RAW  1990656u      // N*C*H*W floats
#define OFF_GSUM 15097856u     // 128 floats
#define OFF_GSQ  15097984u     // 128 floats

// --------------------------------------------------------------------------
// Kernel W: transpose w_dcn [o][c][k] -> wT [k][c][o] for coalesced staging
__global__ void wtrans_kernel(const float* __restrict__ w_dcn,
                              float* __restrict__ wT) {
    int idx = blockIdx.x * 256 + threadIdx.x;
    if (idx >= 9 * 128 * 128) return;
    int o = idx & 127;
    int c = (idx >> 7) & 127;
    int k = idx >> 14;
    wT[idx] = w_dcn[(o * 128 + c) * 9 + k];
}

// --------------------------------------------------------------------------
// Kernel A: fused tm/tr 3x3 convs -> per-pixel sampling coords (py,px) x 9
// py = h + tm0*R0k + tm1*R1k + tr0 ; px = w + tm2*R0k + tm3*R1k + tr1
__global__ void __launch_bounds__(256) offs_kernel(
    const float* __restrict__ x, const float* __restrict__ w_tm,
    const float* __restrict__ b_tm, const float* __restrict__ w_tr,
    const float* __restrict__ b_tr, float* __restrict__ offs) {
    __shared__ float wt[128 * 9 * 8];   // [c][tap][8] (6 used, pad for align)
    int t = threadIdx.x;
    for (int idx = t; idx < 6912; idx += 256) {
        int j = idx % 6;
        int rest = idx / 6;
        int tap = rest % 9;
        int c = rest / 9;
        float v = (j < 4) ? w_tm[(j * 128 + c) * 9 + tap]
                          : w_tr[((j - 4) * 128 + c) * 9 + tap];
        wt[rest * 8 + j] = v;
    }
    __syncthreads();
    int p = blockIdx.x * 256 + t;       // 400 blocks * 256 = 102400 exact
    int n = p / HW;
    int hw = p - n * HW;
    int h = hw / Ww;
    int w = hw - h * Ww;
    int addr[9];
    float msk[9];
#pragma unroll
    for (int tap = 0; tap < 9; ++tap) {
        int dy = tap / 3 - 1, dx = tap % 3 - 1;
        int yy = h + dy, xx = w + dx;
        bool v = (yy >= 0) && (yy < Hh) && (xx >= 0) && (xx < Ww);
        addr[tap] = v ? yy * Ww + xx : 0;
        msk[tap] = v ? 1.f : 0.f;
    }
    float a0 = 0, a1 = 0, a2 = 0, a3 = 0, a4 = 0, a5 = 0;
    const float* xn = x + n * Cc * HW;
    for (int c = 0; c < Cc; ++c) {
        const float* xc = xn + c * HW;
#pragma unroll
        for (int tap = 0; tap < 9; ++tap) {
            float v = msk[tap] * xc[addr[tap]];
            const float* wp = &wt[(c * 9 + tap) * 8];
            float4 w4 = *(const float4*)wp;
            float2 w2 = *(const float2*)(wp + 4);
            a0 += v * w4.x; a1 += v * w4.y; a2 += v * w4.z; a3 += v * w4.w;
            a4 += v * w2.x; a5 += v * w2.y;
        }
    }
    a0 += b_tm[0]; a1 += b_tm[1]; a2 += b_tm[2]; a3 += b_tm[3];
    a4 += b_tr[0]; a5 += b_tr[1];
    float* op = offs + (size_t)p * 18;
#pragma unroll
    for (int k = 0; k < 9; ++k) {
        float r0 = (float)(k / 3) - 1.f;
        float r1 = (float)(k % 3) - 1.f;
        op[k * 2 + 0] = (float)h + a0 * r0 + a1 * r1 + a4;
        op[k * 2 + 1] = (float)w + a2 * r0 + a3 * r1 + a5;
    }
}

// --------------------------------------------------------------------------
// Kernel B: deformable conv. Block = 32 pixels x 128 out channels.
// Per (k, c-half): bilinear-sample S[128c][32p] into LDS (c-half staged once
// for full 128c at ch==0), weight slice wS[64c][128o] in LDS, 4x4 register
// tile fp32 matmul. Epilogue: raw out + per-(n,group) atomic sum/sumsq.
__global__ void __launch_bounds__(256) dcn_kernel(
    const float* __restrict__ x, const float* __restrict__ offs,
    const float* __restrict__ wT, float* __restrict__ raw,
    float* __restrict__ gsum, float* __restrict__ gsq) {
    __shared__ float S[Cc * 32];        // 16 KB  [c][p]
    __shared__ float wS[64 * 128];      // 32 KB  [c'][o]
    int t = threadIdx.x;
    int pb = blockIdx.x * 32;
    int n = pb / HW;
    int pl = t & 31;                    // staging pixel
    int c0 = t >> 5;                    // staging channel base 0..7
    int p = pb + pl;
    // matmul ids
    int tp = t & 7;                     // pixel group (4 pixels)
    int to = t >> 3;                    // out group (4 ch) == GN group
    float acc[4][4];
#pragma unroll
    for (int i = 0; i < 4; ++i)
#pragma unroll
        for (int j = 0; j < 4; ++j) acc[i][j] = 0.f;
    const float* xn = x + n * Cc * HW;

    for (int k = 0; k < 9; ++k) {
        // ---- sampling coords for my pixel ----
        float py = offs[(size_t)p * 18 + k * 2 + 0];
        float px = offs[(size_t)p * 18 + k * 2 + 1];
        float y0f = floorf(py), x0f = floorf(px);
        float fy = py - y0f, fx = px - x0f;
        int y0 = (int)y0f, xi0 = (int)x0f;
        int y1 = y0 + 1, xi1 = xi0 + 1;
        float w00 = (1.f - fy) * (1.f - fx), w01 = (1.f - fy) * fx;
        float w10 = fy * (1.f - fx), w11 = fy * fx;
        bool vy0 = (unsigned)y0 < (unsigned)Hh, vy1 = (unsigned)y1 < (unsigned)Hh;
        bool vx0 = (unsigned)xi0 < (unsigned)Ww, vx1 = (unsigned)xi1 < (unsigned)Ww;
        w00 = (vy0 && vx0) ? w00 : 0.f;
        w01 = (vy0 && vx1) ? w01 : 0.f;
        w10 = (vy1 && vx0) ? w10 : 0.f;
        w11 = (vy1 && vx1) ? w11 : 0.f;
        int cy0 = vy0 ? y0 : 0, cy1 = vy1 ? y1 : 0;
        int cx0 = vx0 ? xi0 : 0, cx1 = vx1 ? xi1 : 0;
        int o00 = cy0 * Ww + cx0, o01 = cy0 * Ww + cx1;
        int o10 = cy1 * Ww + cx0, o11 = cy1 * Ww + cx1;

        for (int ch = 0; ch < 2; ++ch) {
            __syncthreads();            // prev matmul done before overwrite
            if (ch == 0) {
                // stage full S for this k: 128c x 32p
#pragma unroll
                for (int pass = 0; pass < 16; ++pass) {
                    int c = pass * 8 + c0;
                    const float* xc = xn + c * HW;
                    float s = w00 * xc[o00] + w01 * xc[o01] +
                              w10 * xc[o10] + w11 * xc[o11];
                    S[c * 32 + pl] = s;
                }
            }
            // stage weight slice: wT[k][ch*64 + c'][o], 8192 floats
            {
                const float* wk = wT + k * 16384 + ch * 8192;
#pragma unroll
                for (int i = 0; i < 8; ++i) {
                    int idx = t * 4 + i * 1024;
                    *(float4*)&wS[idx] = *(const float4*)&wk[idx];
                }
            }
            __syncthreads();
            int cbase = ch * 64;
#pragma unroll 4
            for (int c = 0; c < 64; ++c) {
                float4 a = *(const float4*)&S[(cbase + c) * 32 + tp * 4];
                float4 b = *(const float4*)&wS[c * 128 + to * 4];
                acc[0][0] += a.x * b.x; acc[0][1] += a.x * b.y;
                acc[0][2] += a.x * b.z; acc[0][3] += a.x * b.w;
                acc[1][0] += a.y * b.x; acc[1][1] += a.y * b.y;
                acc[1][2] += a.y * b.z; acc[1][3] += a.y * b.w;
                acc[2][0] += a.z * b.x; acc[2][1] += a.z * b.y;
                acc[2][2] += a.z * b.z; acc[2][3] += a.z * b.w;
                acc[3][0] += a.w * b.x; acc[3][1] += a.w * b.y;
                acc[3][2] += a.w * b.z; acc[3][3] += a.w * b.w;
            }
        }
    }
    // ---- epilogue: raw out + group sums ----
    int hwbase = (pb - n * HW) + tp * 4;
#pragma unroll
    for (int oi = 0; oi < 4; ++oi) {
        int o = to * 4 + oi;
        float4 v = make_float4(acc[0][oi], acc[1][oi], acc[2][oi], acc[3][oi]);
        *(float4*)&raw[(size_t)(n * Cc + o) * HW + hwbase] = v;
    }
    float lsum = 0.f, lsq = 0.f;
#pragma unroll
    for (int i = 0; i < 4; ++i)
#pragma unroll
        for (int j = 0; j < 4; ++j) {
            lsum += acc[i][j];
            lsq += acc[i][j] * acc[i][j];
        }
    __syncthreads();
    float* red = S;                     // reuse LDS
    red[to * 8 + tp] = lsum;
    red[256 + to * 8 + tp] = lsq;
    __syncthreads();
    if (tp == 0) {
        float s = 0.f, q = 0.f;
#pragma unroll
        for (int i = 0; i < 8; ++i) {
            s += red[to * 8 + i];
            q += red[256 + to * 8 + i];
        }
        atomicAdd(&gsum[n * 32 + to], s);
        atomicAdd(&gsq[n * 32 + to], q);
    }
}

// --------------------------------------------------------------------------
// Kernel C: GroupNorm finalize + residual + ReLU (float4)
__global__ void __launch_bounds__(256) finish_kernel(
    const float* __restrict__ raw, const float* __restrict__ x,
    const float* __restrict__ gsum, const float* __restrict__ gsq,
    const float* __restrict__ gamma, const float* __restrict__ beta,
    float* __restrict__ out) {
    int i = blockIdx.x * 256 + threadIdx.x;   // float4 index, 3276800 total
    int e = i * 4;
    int n = e / (Cc * HW);
    int rem = e - n * (Cc * HW);
    int c = rem / HW;
    int g = c >> 2;
    const float inv = 1.f / 102400.f;
    float mu = gsum[n * 32 + g] * inv;
    float var = gsq[n * 32 + g] * inv - mu * mu;
    float rs = rsqrtf(var + 1e-5f);
    float sc = gamma[c] * rs;
    float sh = beta[c] - mu * sc;
    float4 v = *(const float4*)&raw[e];
    float4 xv = *(const float4*)&x[e];
    float4 r;
    r.x = fmaxf(v.x * sc + sh + xv.x, 0.f);
    r.y = fmaxf(v.y * sc + sh + xv.y, 0.f);
    r.z = fmaxf(v.z * sc + sh + xv.z, 0.f);
    r.w = fmaxf(v.w * sc + sh + xv.w, 0.f);
    *(float4*)&out[e] = r;
}

// --------------------------------------------------------------------------
extern "C" void kernel_launch(void* const* d_in, const int* in_sizes, int n_in,
                              void* d_out, int out_size, void* d_ws, size_t ws_size,
                              hipStream_t stream) {
    const float* x      = (const float*)d_in[0];
    const float* w_tm   = (const float*)d_in[1];
    const float* b_tm   = (const float*)d_in[2];
    const float* w_tr   = (const float*)d_in[3];
    const float* b_tr   = (const float*)d_in[4];
    const float* w_dcn  = (const float*)d_in[5];
    const float* gamma  = (const float*)d_in[6];
    const float* beta   = (const float*)d_in[7];
    float* ws   = (float*)d_ws;
    float* offs = ws + OFF_OFFS;
    float* wT   = ws + OFF_WT;
    float* raw  = ws + OFF_RAW;
    float* gsum = ws + OFF_GSUM;
    float* gsq  = ws + OFF_GSQ;
    float* out  = (float*)d_out;

    hipMemsetAsync(gsum, 0, 256 * sizeof(float), stream);  // gsum+gsq
    wtrans_kernel<<<576, 256, 0, stream>>>(w_dcn, wT);
    offs_kernel<<<400, 256, 0, stream>>>(x, w_tm, b_tm, w_tr, b_tr, offs);
    dcn_kernel<<<3200, 256, 0, stream>>>(x, offs, wT, raw, gsum, gsq);
    finish_kernel<<<12800, 256, 0, stream>>>(raw, x, gsum, gsq, gamma, beta, out);
}